// Round 4
// baseline (834.394 us; speedup 1.0000x reference)
//
#include <hip/hip_runtime.h>

typedef unsigned short u16;
typedef __attribute__((ext_vector_type(8))) short bfrag;     // 8 bf16 (4 VGPRs) MFMA A/B
typedef __attribute__((ext_vector_type(4))) float ffrag;     // 4 f32 MFMA C/D
typedef __attribute__((ext_vector_type(4))) float f4;
typedef __attribute__((ext_vector_type(4))) _Float16 h4;     // fn: xyz + pad, 8 B

#define NVERT 35709
#define NFACE 70789
#define NV3   107127
#define NB    128

// ---- workspace byte layout (all intermediates BATCH-MAJOR-FASTEST: [row][128 batches]) ----
#define SHAPE_OFF 0ull            // f32, shpT[j][128]          (54,849,024 B)
#define TEX_OFF   54849024ull     // u16 bf16, texT[j][128]     (27,424,512 B)
#define FN_OFF    82273536ull     // h4, fnT[f][128]            (72,487,936 B)
#define CPACK_OFF 154761472ull    // u16 bf16, cpack[b][256] = [id80|0*16|ex64|tex80|0*16]
#define ROT_OFF   154827008ull    // f32, rotT[9][128]
#define G_OFF     154831616ull    // f32, GT[27][128]
#define TRANS_OFF 154845440ull    // f32, trT[3][128]
#define MEAN_OFF  154846976ull    // f32, 3
#define PART_OFF  154847040ull    // f32, 64*3 partial sums for mean

// ---- output element offsets (f32 out, reference layout [b][...]) ----
#define LMS_BASE  13712256ull     // after face_color (B*NV*3)
#define ST_BASE   13729664ull     // after lms (B*68*2)

__device__ __forceinline__ float b2f(u16 s) {
  union { unsigned u; float f; } v; v.u = ((unsigned)s) << 16; return v.f;
}
__device__ __forceinline__ u16 f2b(float x) {  // f32 -> bf16 RNE
  union { float f; unsigned u; } v; v.f = x;
  unsigned r = v.u + 0x7FFFu + ((v.u >> 16) & 1u);
  return (u16)(r >> 16);
}
__device__ __forceinline__ bfrag cvt8nt(const float* p) {  // 8 f32 (nt) -> 8 bf16
  f4 a = __builtin_nontemporal_load((const f4*)p);
  f4 b = __builtin_nontemporal_load((const f4*)(p + 4));
  bfrag r;
  r[0] = (short)f2b(a.x); r[1] = (short)f2b(a.y); r[2] = (short)f2b(a.z); r[3] = (short)f2b(a.w);
  r[4] = (short)f2b(b.x); r[5] = (short)f2b(b.y); r[6] = (short)f2b(b.z); r[7] = (short)f2b(b.w);
  return r;
}

// K0: partial sums of meanshape over vertices (64 blocks x 3 comps)
__global__ __launch_bounds__(256) void k_mean(const float* __restrict__ ms, float* __restrict__ part) {
  __shared__ float s[3];
  if (threadIdx.x < 3) s[threadIdx.x] = 0.f;
  __syncthreads();
  float a0 = 0.f, a1 = 0.f, a2 = 0.f;
  for (int v = blockIdx.x * 256 + threadIdx.x; v < NVERT; v += 64 * 256) {
    a0 += ms[v * 3 + 0];
    a1 += ms[v * 3 + 1];
    a2 += ms[v * 3 + 2];
  }
  atomicAdd(&s[0], a0); atomicAdd(&s[1], a1); atomicAdd(&s[2], a2);
  __syncthreads();
  if (threadIdx.x < 3) part[blockIdx.x * 3 + threadIdx.x] = s[threadIdx.x];
}

// K1: finalize mean; bf16-packed coeffs; TRANSPOSED params rotT[9][128], GT[27][128], trT[3][128].
__global__ __launch_bounds__(128) void k_params(const float* __restrict__ coeff, u16* __restrict__ cpack,
                                                float* __restrict__ rotT, float* __restrict__ GT,
                                                float* __restrict__ trT, const float* __restrict__ part,
                                                float* __restrict__ mean) {
  int b = threadIdx.x;
  if (b < 3) {
    float s = 0.f;
    for (int i = 0; i < 64; i++) s += part[i * 3 + b];
    mean[b] = s * (1.0f / (float)NVERT);
  }
  const float* c = coeff + b * 257;
  u16* cp = cpack + b * 256;
  for (int k = 0; k < 80; k++) cp[k] = f2b(c[k]);            // id
  for (int k = 80; k < 96; k++) cp[k] = 0;                   // pad
  for (int k = 0; k < 64; k++) cp[96 + k] = f2b(c[80 + k]);  // ex
  for (int k = 0; k < 80; k++) cp[160 + k] = f2b(c[144 + k]);// tex
  for (int k = 240; k < 256; k++) cp[k] = 0;                 // pad
  float ax = c[224], ay = c[225], az = c[226];
  float sx = sinf(ax), cx = cosf(ax);
  float sy = sinf(ay), cy = cosf(ay);
  float sz = sinf(az), cz = cosf(az);
  rotT[0 * 128 + b] = cz * cy;
  rotT[1 * 128 + b] = cz * sy * sx - sz * cx;
  rotT[2 * 128 + b] = sz * sx + cz * sy * cx;
  rotT[3 * 128 + b] = sz * cy;
  rotT[4 * 128 + b] = cz * cx + sz * sy * sx;
  rotT[5 * 128 + b] = sz * sy * cx - cz * sx;
  rotT[6 * 128 + b] = -sy;
  rotT[7 * 128 + b] = cy * sx;
  rotT[8 * 128 + b] = cy * cx;
  for (int cc = 0; cc < 9; cc++)
    for (int d = 0; d < 3; d++)
      GT[(cc * 3 + d) * 128 + b] = c[227 + d * 9 + cc] + (cc == 0 ? 0.8f : 0.0f);
  trT[0 * 128 + b] = c[254];
  trT[1 * 128 + b] = c[255];
  trT[2 * 128 + b] = c[256];
}

// K2: MFMA GEMM producing TRANSPOSED outputs: A = base rows (m=j), B = coeff (n=b).
// Same fragment register data as before; only intrinsic argument order swapped.
// D: row(quad*4+r)=j, col(lane&15)=b. Store shpT[j][b], texT[j][b].
__global__ __launch_bounds__(256) void k_gemm(const float* __restrict__ idB, const float* __restrict__ exB,
                                              const float* __restrict__ txB, const float* __restrict__ ms,
                                              const float* __restrict__ mt, const u16* __restrict__ cpack,
                                              const float* __restrict__ meanc,
                                              float* __restrict__ shpT, u16* __restrict__ texT) {
  int wave = threadIdx.x >> 6, lane = threadIdx.x & 63;
  int jt = blockIdx.x * 4 + wave;
  int col = lane & 15, quad = lane >> 4;
  int j = jt * 16 + col;                       // A-fragment row (m = j)
  int jc = (j < NV3) ? j : (NV3 - 1);          // clamped: loads always in-bounds
  bfrag z8 = {0, 0, 0, 0, 0, 0, 0, 0};
  bfrag bid[3], bex[2], btx[3];
  const float* rowI = idB + (size_t)jc * 80;
  const float* rowT = txB + (size_t)jc * 80;
  const float* rowE = exB + (size_t)jc * 64;
#pragma unroll
  for (int f = 0; f < 3; f++) {
    int k = f * 32 + quad * 8;
    bool ok = (k < 80);
    int ks = ok ? k : 0;
    bfrag vi = cvt8nt(rowI + ks);
    bfrag vt = cvt8nt(rowT + ks);
    bid[f] = ok ? vi : z8;
    btx[f] = ok ? vt : z8;
  }
#pragma unroll
  for (int f = 0; f < 2; f++) {
    int k = f * 32 + quad * 8;                 // <= 56, always in-bounds
    bex[f] = cvt8nt(rowE + k);
  }
  // per-output-row constants: rows jr = jt*16 + quad*4 + r
  float m0 = meanc[0], m1 = meanc[1], m2 = meanc[2];
  int jr0 = jt * 16 + quad * 4;
  float msv[4], mtv[4], mcv[4];
#pragma unroll
  for (int r = 0; r < 4; r++) {
    int jr = jr0 + r;
    int jrc = (jr < NV3) ? jr : (NV3 - 1);
    msv[r] = ms[jrc];
    mtv[r] = mt[jrc];
    int md = jrc % 3;
    mcv[r] = (md == 0) ? m0 : (md == 1 ? m1 : m2);
  }

  for (int bt = 0; bt < 8; bt++) {
    const u16* cp = cpack + (size_t)(bt * 16 + col) * 256;  // coeff frag: n=lane&15 -> batch
    ffrag accS = {0.f, 0.f, 0.f, 0.f};
    ffrag accT = {0.f, 0.f, 0.f, 0.f};
#pragma unroll
    for (int f = 0; f < 3; f++) {
      bfrag a = *(const bfrag*)(cp + f * 32 + quad * 8);
      accS = __builtin_amdgcn_mfma_f32_16x16x32_bf16(bid[f], a, accS, 0, 0, 0);
    }
#pragma unroll
    for (int f = 0; f < 2; f++) {
      bfrag a = *(const bfrag*)(cp + 96 + f * 32 + quad * 8);
      accS = __builtin_amdgcn_mfma_f32_16x16x32_bf16(bex[f], a, accS, 0, 0, 0);
    }
#pragma unroll
    for (int f = 0; f < 3; f++) {
      bfrag a = *(const bfrag*)(cp + 160 + f * 32 + quad * 8);
      accT = __builtin_amdgcn_mfma_f32_16x16x32_bf16(btx[f], a, accT, 0, 0, 0);
    }
#pragma unroll
    for (int r = 0; r < 4; r++) {
      int jr = jr0 + r;
      if (jr < NV3) {
        size_t o = (size_t)jr * 128 + bt * 16 + col;
        shpT[o] = accS[r] + msv[r] - mcv[r];
        texT[o] = f2b(accT[r] + mtv[r]);
      }
    }
  }
}

// K3: face normals, batch-fastest. Block = 2 faces x 128 batches; face index wave-uniform
// (readfirstlane -> scalar tri loads); vertex gathers are fully coalesced 512 B loads.
__global__ __launch_bounds__(256) void k_fn(const float* __restrict__ shpT, const int* __restrict__ tri,
                                            h4* __restrict__ fnT) {
  int b = threadIdx.x & 127;
  int f = blockIdx.x * 2 + (threadIdx.x >> 7);
  f = __builtin_amdgcn_readfirstlane(f);       // wave-uniform by construction
  if (f >= NFACE) return;
  int i0 = tri[f * 3 + 0] - 1, i1 = tri[f * 3 + 1] - 1, i2 = tri[f * 3 + 2] - 1;  // scalar
  float x1 = shpT[(size_t)(i0 * 3 + 0) * 128 + b];
  float y1 = shpT[(size_t)(i0 * 3 + 1) * 128 + b];
  float z1 = shpT[(size_t)(i0 * 3 + 2) * 128 + b];
  float x2 = shpT[(size_t)(i1 * 3 + 0) * 128 + b];
  float y2 = shpT[(size_t)(i1 * 3 + 1) * 128 + b];
  float z2 = shpT[(size_t)(i1 * 3 + 2) * 128 + b];
  float x3 = shpT[(size_t)(i2 * 3 + 0) * 128 + b];
  float y3 = shpT[(size_t)(i2 * 3 + 1) * 128 + b];
  float z3 = shpT[(size_t)(i2 * 3 + 2) * 128 + b];
  float e1x = x1 - x2, e1y = y1 - y2, e1z = z1 - z2;
  float e2x = x2 - x3, e2y = y2 - y3, e2z = z2 - z3;
  h4 st;
  st.x = (_Float16)(e1y * e2z - e1z * e2y);
  st.y = (_Float16)(e1z * e2x - e1x * e2z);
  st.z = (_Float16)(e1x * e2y - e1y * e2x);
  st.w = (_Float16)0.f;
  fnT[(size_t)f * 128 + b] = st;               // 64 lanes x 8 B consecutive
}

// K4: vn gather (coalesced over batch), normalize, rotate, illuminate, write outputs.
// Block = 2 vertices x 128 batches; pbuf indices wave-uniform -> scalar; fn gathers coalesced.
// Output writes are [b][...]-layout scatters: XCD v-affinity keeps partial lines on one XCD's L2.
#define FI_VPX 4464   // ceil(NVERT/8), even
#define FI_BPX 2232   // blocks per XCD (2 verts each)
__global__ __launch_bounds__(256) void k_final(const float* __restrict__ shpT, const u16* __restrict__ texT,
                                               const h4* __restrict__ fnT, const int* __restrict__ pbuf,
                                               const float* __restrict__ rotT, const float* __restrict__ GT,
                                               const float* __restrict__ trT, float* __restrict__ out) {
  int b = threadIdx.x & 127;
  int g = blockIdx.x;
  int xcd = g & 7;
  int v = xcd * FI_VPX + (g >> 3) * 2 + (threadIdx.x >> 7);
  v = __builtin_amdgcn_readfirstlane(v);       // wave-uniform
  if (v >= NVERT) return;
  const int* p = pbuf + (size_t)v * 8;         // scalar loads
  float vx = 0.f, vy = 0.f, vz = 0.f;
#pragma unroll
  for (int i = 0; i < 8; i++) {
    int id = p[i] - 1;                         // in [0, NFACE]; NFACE == appended zero row
    if (id < NFACE) {                          // uniform branch
      h4 q = fnT[(size_t)id * 128 + b];        // coalesced 512 B gather
      vx += (float)q.x; vy += (float)q.y; vz += (float)q.z;
    }
  }
  float n2 = vx * vx + vy * vy + vz * vz;
  float inv = rsqrtf(fmaxf(n2, 1e-30f));
  vx *= inv; vy *= inv; vz *= inv;
  float M0 = rotT[0 * 128 + b], M1 = rotT[1 * 128 + b], M2 = rotT[2 * 128 + b];
  float M3 = rotT[3 * 128 + b], M4 = rotT[4 * 128 + b], M5 = rotT[5 * 128 + b];
  float M6 = rotT[6 * 128 + b], M7 = rotT[7 * 128 + b], M8 = rotT[8 * 128 + b];
  float nx = vx * M0 + vy * M1 + vz * M2;
  float ny = vx * M3 + vy * M4 + vz * M5;
  float nz = vx * M6 + vy * M7 + vz * M8;
  float sx = shpT[(size_t)(v * 3 + 0) * 128 + b];
  float sy = shpT[(size_t)(v * 3 + 1) * 128 + b];
  float sz = shpT[(size_t)(v * 3 + 2) * 128 + b];
  float ox = sx * M0 + sy * M1 + sz * M2 + trT[0 * 128 + b];
  float oy = sx * M3 + sy * M4 + sz * M5 + trT[1 * 128 + b];
  float oz = sx * M6 + sy * M7 + sz * M8 + trT[2 * 128 + b];
  // SH lighting
  const float kc1 = 1.7724539f;                // a1*c1 = sqrt(pi)
  const float kc2 = 2.4270324f;                // a2*c2
  const float kd0 = 0.28867513f;               // 0.5/sqrt(3)
  float Y[9];
  Y[0] = 0.8862269f;                           // a0*c0
  Y[1] = -kc1 * ny;
  Y[2] = kc1 * nz;
  Y[3] = -kc1 * nx;
  Y[4] = kc2 * nx * ny;
  Y[5] = -kc2 * ny * nz;
  Y[6] = kc2 * kd0 * (3.f * nz * nz - 1.f);
  Y[7] = -kc2 * nx * nz;
  Y[8] = kc2 * 0.5f * (nx * nx - ny * ny);
  size_t ofc = (size_t)b * NV3 + (size_t)v * 3;
#pragma unroll
  for (int d = 0; d < 3; d++) {
    float L = 0.f;
#pragma unroll
    for (int cc = 0; cc < 9; cc++) L += Y[cc] * GT[(cc * 3 + d) * 128 + b];
    float t = b2f(texT[(size_t)(v * 3 + d) * 128 + b]);
    __builtin_nontemporal_store(t * L, out + ofc + d);
  }
  __builtin_nontemporal_store(ox, out + ST_BASE + ofc + 0);
  __builtin_nontemporal_store(oy, out + ST_BASE + ofc + 1);
  __builtin_nontemporal_store(oz, out + ST_BASE + ofc + 2);
}

// K5: landmarks — block per keypoint, lanes over batches; coalesced shpT/param reads.
__global__ __launch_bounds__(128) void k_lms(const float* __restrict__ shpT, const int* __restrict__ kp,
                                             const float* __restrict__ rotT, const float* __restrict__ trT,
                                             float* __restrict__ out) {
  int b = threadIdx.x;
  int t = blockIdx.x;
  int v = kp[t];                               // scalar
  float sx = shpT[(size_t)(v * 3 + 0) * 128 + b];
  float sy = shpT[(size_t)(v * 3 + 1) * 128 + b];
  float sz = shpT[(size_t)(v * 3 + 2) * 128 + b];
  float M0 = rotT[0 * 128 + b], M1 = rotT[1 * 128 + b], M2 = rotT[2 * 128 + b];
  float M3 = rotT[3 * 128 + b], M4 = rotT[4 * 128 + b], M5 = rotT[5 * 128 + b];
  float M6 = rotT[6 * 128 + b], M7 = rotT[7 * 128 + b], M8 = rotT[8 * 128 + b];
  float ox = sx * M0 + sy * M1 + sz * M2 + trT[0 * 128 + b];
  float oy = sx * M3 + sy * M4 + sz * M5 + trT[1 * 128 + b];
  float oz = sx * M6 + sy * M7 + sz * M8 + trT[2 * 128 + b];
  float w = 10.f - oz;                         // pts@[1,1,-1] + [0,0,10]
  float invw = 1.0f / w;
  float lx = 1015.f * ox * invw + 128.f;       // FOCAL*x/w + half
  float ly = 1015.f * oy * invw + 128.f;
  size_t o = LMS_BASE + ((size_t)b * 68 + t) * 2;
  out[o + 0] = lx;
  out[o + 1] = 256.f - ly;                     // IMG - y
}

extern "C" void kernel_launch(void* const* d_in, const int* in_sizes, int n_in,
                              void* d_out, int out_size, void* d_ws, size_t ws_size,
                              hipStream_t stream) {
  const float* coeff     = (const float*)d_in[0];
  const float* meanshape = (const float*)d_in[1];
  const float* idB       = (const float*)d_in[2];
  const float* exB       = (const float*)d_in[3];
  const float* meantex   = (const float*)d_in[4];
  const float* txB       = (const float*)d_in[5];
  const int* tri         = (const int*)d_in[6];
  const int* pbuf        = (const int*)d_in[7];
  const int* kp          = (const int*)d_in[8];
  float* out = (float*)d_out;
  char* ws = (char*)d_ws;
  float* shpT = (float*)(ws + SHAPE_OFF);
  u16* texT   = (u16*)(ws + TEX_OFF);
  h4* fnT     = (h4*)(ws + FN_OFF);
  u16* cpack  = (u16*)(ws + CPACK_OFF);
  float* rotT = (float*)(ws + ROT_OFF);
  float* GT   = (float*)(ws + G_OFF);
  float* trT  = (float*)(ws + TRANS_OFF);
  float* mean = (float*)(ws + MEAN_OFF);
  float* part = (float*)(ws + PART_OFF);

  k_mean<<<64, 256, 0, stream>>>(meanshape, part);
  k_params<<<1, 128, 0, stream>>>(coeff, cpack, rotT, GT, trT, part, mean);
  k_gemm<<<1674, 256, 0, stream>>>(idB, exB, txB, meanshape, meantex, cpack, mean, shpT, texT);
  k_fn<<<(NFACE + 1) / 2, 256, 0, stream>>>(shpT, tri, fnT);
  k_final<<<8 * FI_BPX, 256, 0, stream>>>(shpT, texT, fnT, pbuf, rotT, GT, trT, out);
  k_lms<<<68, 128, 0, stream>>>(shpT, kp, rotT, trT, out);
}